// Round 2
// baseline (23.058 us; speedup 1.0000x reference)
//
#include <hip/hip_runtime.h>

// RecurrentLTI as a single complex first-order scan (see round-0 derivation):
// S_{k+1} = lam*S_k + u_k, lam = A[0][0] - i*A[0][1];
// y_k = Re(Gamma * S_{k+1}) + d*u_k,
// Gamma = sum_i (c[2i] - i c[2i+1]) (b[2i] + i b[2i+1]).
//
// Single 1024-thread workgroup, ONE dispatch (was 3 -> launch-overhead bound):
//   thread t owns elements [64t, 64t+64) in registers;
//   phase1: per-thread aggregate; phase2: in-block scan of 1024 aggregates
//   (wave Kogge-Stone, mult lam^64, + cross-wave 16-scan, mult lam^4096);
//   phase3: rescan with exclusive carry, write y as float4.

struct C2 { float r, i; };

__device__ __forceinline__ C2 cmul(C2 a, C2 b) {
    return C2{ a.r * b.r - a.i * b.i, a.r * b.i + a.i * b.r };
}
// acc + p * x
__device__ __forceinline__ C2 cfma(C2 p, C2 x, C2 acc) {
    C2 o;
    o.r = fmaf(p.r, x.r, fmaf(-p.i, x.i, acc.r));
    o.i = fmaf(p.r, x.i, fmaf( p.i, x.r, acc.i));
    return o;
}

#define CH 64   // elements per thread; 1024 threads * 64 = 65536

__global__ __launch_bounds__(1024) void lti_fused(
    const float* __restrict__ u, const float* __restrict__ A,
    const float* __restrict__ b, const float* __restrict__ c,
    const float* __restrict__ dsc, float* __restrict__ y)
{
    const int t    = threadIdx.x;
    const int lane = t & 63;
    const int w    = t >> 6;

    __shared__ float2 shW[16];
    __shared__ float2 shG[4];

    const C2 lam{ A[0], -A[1] };
    const float nlami = -lam.i;

    // ---- load per-thread chunk (64 floats) into registers ----
    float uu[CH];
    const float4* up = reinterpret_cast<const float4*>(u) + t * (CH / 4);
#pragma unroll
    for (int j = 0; j < CH / 4; ++j) {
        float4 q = up[j];
        uu[4 * j + 0] = q.x; uu[4 * j + 1] = q.y;
        uu[4 * j + 2] = q.z; uu[4 * j + 3] = q.w;
    }

    // ---- Gamma partials (threads 0..255 cover the 256 2x2 blocks) ----
    C2 g{ 0.f, 0.f };
    if (t < 256) {
        const float b1 = b[2 * t], b2 = b[2 * t + 1];
        const float c1 = c[2 * t], c2 = c[2 * t + 1];
        g.r = fmaf(b1, c1, b2 * c2);
        g.i = fmaf(c1, b2, -(c2 * b1));
    }
#pragma unroll
    for (int d = 32; d > 0; d >>= 1) {
        g.r += __shfl_xor(g.r, d, 64);
        g.i += __shfl_xor(g.i, d, 64);
    }
    if (lane == 0 && w < 4) shG[w] = make_float2(g.r, g.i);

    // ---- phase 1: per-thread aggregate  v = sum_k lam^{63-k} u_k ----
    C2 v{ 0.f, 0.f };
#pragma unroll
    for (int k = 0; k < CH; ++k) {
        const float vr = v.r;
        v.r = fmaf(lam.r, v.r, fmaf(nlami, v.i, uu[k]));
        v.i = fmaf(lam.i, vr, lam.r * v.i);
    }

    // ---- powers of lam^64 ----
    C2 pwM[6];               // (lam^64)^(2^s), s = 0..5
    {
        C2 m = lam;
#pragma unroll
        for (int s = 0; s < 6; ++s) m = cmul(m, m);     // lam^64
        pwM[0] = m;
#pragma unroll
        for (int s = 1; s < 6; ++s) pwM[s] = cmul(pwM[s - 1], pwM[s - 1]);
    }
    C2 pw2[4];               // (lam^4096)^(2^s), s = 0..3
    pw2[0] = cmul(pwM[5], pwM[5]);
#pragma unroll
    for (int s = 1; s < 4; ++s) pw2[s] = cmul(pw2[s - 1], pw2[s - 1]);

    // ---- wave-level KS inclusive scan of aggregates (mult lam^64) ----
    C2 sv = v;
#pragma unroll
    for (int s = 0; s < 6; ++s) {
        const int d = 1 << s;
        float pr = __shfl_up(sv.r, d, 64);
        float pi = __shfl_up(sv.i, d, 64);
        if (lane >= d) sv = cfma(pwM[s], C2{ pr, pi }, sv);
    }
    if (lane == 63) shW[w] = make_float2(sv.r, sv.i);
    __syncthreads();

    // ---- cross-wave scan of 16 wave totals (mult lam^4096), wave 0 ----
    if (w == 0) {
        C2 x = (lane < 16) ? C2{ shW[lane].x, shW[lane].y } : C2{ 0.f, 0.f };
#pragma unroll
        for (int s = 0; s < 4; ++s) {
            const int d = 1 << s;
            float pr = __shfl_up(x.r, d, 64);
            float pi = __shfl_up(x.i, d, 64);
            if (lane >= d && lane < 16) x = cfma(pw2[s], C2{ pr, pi }, x);
        }
        if (lane < 16) shW[lane] = make_float2(x.r, x.i);
    }
    __syncthreads();

    // ---- exclusive carry E for this thread ----
    float pr1 = __shfl_up(sv.r, 1, 64);
    float pi1 = __shfl_up(sv.i, 1, 64);
    C2 E = (lane > 0) ? C2{ pr1, pi1 } : C2{ 0.f, 0.f };
    if (w > 0) {
        // E += (lam^64)^lane * (inclusive through wave w-1)
        C2 p{ 1.f, 0.f };
#pragma unroll
        for (int s = 0; s < 6; ++s)
            if ((lane >> s) & 1) p = cmul(p, pwM[s]);
        const float2 wp = shW[w - 1];
        E = cfma(p, C2{ wp.x, wp.y }, E);
    }

    // ---- Gamma total + d ----
    const float2 g0 = shG[0], g1 = shG[1], g2 = shG[2], g3 = shG[3];
    const float Gr  = g0.x + g1.x + g2.x + g3.x;
    const float Gi  = g0.y + g1.y + g2.y + g3.y;
    const float nGi = -Gi;
    const float dv  = dsc[0];

    // ---- phase 3: rescan with carry, emit y ----
    C2 s2 = E;
    float4* yp = reinterpret_cast<float4*>(y) + t * (CH / 4);
#pragma unroll
    for (int j = 0; j < CH / 4; ++j) {
        float4 o;
        float* op = &o.x;
#pragma unroll
        for (int q = 0; q < 4; ++q) {
            const float uk = uu[4 * j + q];
            const float vr = s2.r;
            s2.r = fmaf(lam.r, s2.r, fmaf(nlami, s2.i, uk));
            s2.i = fmaf(lam.i, vr, lam.r * s2.i);
            op[q] = fmaf(Gr, s2.r, fmaf(nGi, s2.i, dv * uk));
        }
        yp[j] = o;
    }
}

extern "C" void kernel_launch(void* const* d_in, const int* in_sizes, int n_in,
                              void* d_out, int out_size, void* d_ws, size_t ws_size,
                              hipStream_t stream) {
    const float* u = (const float*)d_in[0];   // [65536]
    const float* A = (const float*)d_in[1];   // [512*512]
    const float* b = (const float*)d_in[2];   // [512]
    const float* c = (const float*)d_in[3];   // [512]
    const float* d = (const float*)d_in[4];   // [1]
    float* y = (float*)d_out;                 // [65536]

    lti_fused<<<1, 1024, 0, stream>>>(u, A, b, c, d, y);
}

// Round 4
// 12.637 us; speedup vs baseline: 1.8247x; 1.8247x over previous
//
#include <hip/hip_runtime.h>

// RecurrentLTI == single complex first-order scan (round-0 derivation):
//   S_{k+1} = lam*S_k + u_k,  lam = A[0][0] - i*A[0][1]
//   y_k = Re(Gamma * S_{k+1}) + d*u_k
//   Gamma = sum_i (c[2i] - i c[2i+1])(b[2i] + i b[2i+1])
//
// 2-dispatch chunked scan, 64 blocks x 256 threads x 4 elems (float4):
//   K1: per-block aggregates (per-thread serial-4, wave KS, LDS combine)
//       + Gamma reduction in block 0.
//   K2: every block redundantly scans the 64 aggregates with wave 0
//       (6 KS steps), folds its carry, rescans its 1024 elems, writes y.

struct C2 { float r, i; };

__device__ __forceinline__ C2 cmul(C2 a, C2 b) {
    return C2{ a.r * b.r - a.i * b.i, a.r * b.i + a.i * b.r };
}
// acc + p * x
__device__ __forceinline__ C2 cfma(C2 p, C2 x, C2 acc) {
    C2 o;
    o.r = fmaf(p.r, x.r, fmaf(-p.i, x.i, acc.r));
    o.i = fmaf(p.r, x.i, fmaf( p.i, x.r, acc.i));
    return o;
}
__device__ __forceinline__ C2 csq(C2 a) { return cmul(a, a); }

// one recurrence step: v = lam*v + uk
__device__ __forceinline__ void step(C2& v, C2 lam, float uk) {
    const float vr = v.r;
    v.r = fmaf(lam.r, v.r, fmaf(-lam.i, v.i, uk));
    v.i = fmaf(lam.i, vr, lam.r * v.i);
}

// ---------------- K1: 64 block aggregates + Gamma ----------------
__global__ __launch_bounds__(256) void k_agg(const float* __restrict__ u,
                                             const float* __restrict__ A,
                                             const float* __restrict__ b,
                                             const float* __restrict__ c,
                                             float2* __restrict__ agg,
                                             float2* __restrict__ gam) {
    const int t = threadIdx.x, lane = t & 63, w = t >> 6;
    __shared__ float2 shW[4];
    __shared__ float2 shG[4];

    const C2 lam{ A[0], -A[1] };

    // pwM[s] = lam^(4*2^s), s=0..5  (for KS over 4-elem segments)
    C2 pwM[6];
    pwM[0] = csq(csq(lam));                       // lam^4
#pragma unroll
    for (int s = 1; s < 6; ++s) pwM[s] = csq(pwM[s - 1]);
    const C2 l256 = csq(pwM[5]);                  // lam^256

    // per-thread serial aggregate over 4 elems
    const float4 q = reinterpret_cast<const float4*>(u)[blockIdx.x * 256 + t];
    C2 v{ 0.f, 0.f };
    step(v, lam, q.x); step(v, lam, q.y); step(v, lam, q.z); step(v, lam, q.w);

    // wave KS over 64 thread-aggregates
    C2 sv = v;
#pragma unroll
    for (int s = 0; s < 6; ++s) {
        const int d = 1 << s;
        float pr = __shfl_up(sv.r, d, 64);
        float pi = __shfl_up(sv.i, d, 64);
        if (lane >= d) sv = cfma(pwM[s], C2{ pr, pi }, sv);
    }
    if (lane == 63) shW[w] = make_float2(sv.r, sv.i);
    __syncthreads();

    if (t == 0) {
        C2 a{ shW[0].x, shW[0].y };
#pragma unroll
        for (int i = 1; i < 4; ++i)
            a = cfma(l256, a, C2{ shW[i].x, shW[i].y });   // shW[i] + lam^256*a
        agg[blockIdx.x] = make_float2(a.r, a.i);
    }

    // ---- Gamma (block 0 only; all 256 threads participate) ----
    if (blockIdx.x == 0) {
        const float b1 = b[2 * t], b2 = b[2 * t + 1];
        const float c1 = c[2 * t], c2 = c[2 * t + 1];
        C2 g;
        g.r = fmaf(b1, c1, b2 * c2);
        g.i = fmaf(c1, b2, -(c2 * b1));
#pragma unroll
        for (int d = 32; d > 0; d >>= 1) {
            g.r += __shfl_xor(g.r, d, 64);
            g.i += __shfl_xor(g.i, d, 64);
        }
        if (lane == 0) shG[w] = make_float2(g.r, g.i);
        __syncthreads();
        if (t == 0) {
            float gr = shG[0].x + shG[1].x + shG[2].x + shG[3].x;
            float gi = shG[0].y + shG[1].y + shG[2].y + shG[3].y;
            gam[0] = make_float2(gr, gi);
        }
    }
}

// ---------------- K2: fold carries, rescan, write y ----------------
__global__ __launch_bounds__(256) void k_scan(const float* __restrict__ u,
                                              const float* __restrict__ A,
                                              const float* __restrict__ dsc,
                                              const float2* __restrict__ agg,
                                              const float2* __restrict__ gam,
                                              float* __restrict__ y) {
    const int t = threadIdx.x, lane = t & 63, w = t >> 6;
    const int blk = blockIdx.x;
    __shared__ float2 shP[64];
    __shared__ float2 shW[4];

    const C2 lam{ A[0], -A[1] };

    C2 pwM[6];
    pwM[0] = csq(csq(lam));                       // lam^4
#pragma unroll
    for (int s = 1; s < 6; ++s) pwM[s] = csq(pwM[s - 1]);
    const C2 l256 = csq(pwM[5]);                  // lam^256

    // wave 0: redundant KS over the 64 block aggregates (seg len 1024)
    if (w == 0) {
        C2 pw2[6];
        pw2[0] = csq(csq(l256));                  // lam^1024
#pragma unroll
        for (int s = 1; s < 6; ++s) pw2[s] = csq(pw2[s - 1]);
        float2 a0 = agg[lane];
        C2 x{ a0.x, a0.y };
#pragma unroll
        for (int s = 0; s < 6; ++s) {
            const int d = 1 << s;
            float pr = __shfl_up(x.r, d, 64);
            float pi = __shfl_up(x.i, d, 64);
            if (lane >= d) x = cfma(pw2[s], C2{ pr, pi }, x);
        }
        shP[lane] = make_float2(x.r, x.i);
    }

    // local serial-4 aggregate + wave KS (same as K1)
    const float4 q = reinterpret_cast<const float4*>(u)[blk * 256 + t];
    C2 v{ 0.f, 0.f };
    step(v, lam, q.x); step(v, lam, q.y); step(v, lam, q.z); step(v, lam, q.w);

    C2 sv = v;
#pragma unroll
    for (int s = 0; s < 6; ++s) {
        const int d = 1 << s;
        float pr = __shfl_up(sv.r, d, 64);
        float pi = __shfl_up(sv.i, d, 64);
        if (lane >= d) sv = cfma(pwM[s], C2{ pr, pi }, sv);
    }
    if (lane == 63) shW[w] = make_float2(sv.r, sv.i);
    __syncthreads();

    // carry entering this wave: block prefix advanced through waves 0..w-1
    C2 cw = (blk == 0) ? C2{ 0.f, 0.f } : C2{ shP[blk - 1].x, shP[blk - 1].y };
    for (int i = 0; i < w; ++i)
        cw = cfma(l256, cw, C2{ shW[i].x, shW[i].y });     // shW[i] + lam^256*cw

    // thread-exclusive carry: E = sv(lane-1) + lam^(4*lane) * cw
    float pr1 = __shfl_up(sv.r, 1, 64);
    float pi1 = __shfl_up(sv.i, 1, 64);
    C2 E = (lane > 0) ? C2{ pr1, pi1 } : C2{ 0.f, 0.f };
    C2 p{ 1.f, 0.f };
#pragma unroll
    for (int s = 0; s < 6; ++s)
        if ((lane >> s) & 1) p = cmul(p, pwM[s]);
    E = cfma(p, cw, E);

    // rescan 4 elems from E, emit y
    const float2 G = gam[0];
    const float dv = dsc[0];
    C2 s2 = E;
    float4 o;
    const float* qe = &q.x;
    float* oe = &o.x;
#pragma unroll
    for (int j = 0; j < 4; ++j) {
        const float uk = qe[j];
        step(s2, lam, uk);
        oe[j] = fmaf(G.x, s2.r, fmaf(-G.y, s2.i, dv * uk));
    }
    reinterpret_cast<float4*>(y)[blk * 256 + t] = o;
}

extern "C" void kernel_launch(void* const* d_in, const int* in_sizes, int n_in,
                              void* d_out, int out_size, void* d_ws, size_t ws_size,
                              hipStream_t stream) {
    const float* u = (const float*)d_in[0];   // [65536]
    const float* A = (const float*)d_in[1];   // [512*512]
    const float* b = (const float*)d_in[2];   // [512]
    const float* c = (const float*)d_in[3];   // [512]
    const float* d = (const float*)d_in[4];   // [1]
    float* y = (float*)d_out;                 // [65536]

    float2* agg = (float2*)d_ws;              // 64 block aggregates
    float2* gam = agg + 64;                   // Gamma

    k_agg<<<64, 256, 0, stream>>>(u, A, b, c, agg, gam);
    k_scan<<<64, 256, 0, stream>>>(u, A, d, agg, gam, y);
}